// Round 6
// baseline (482.255 us; speedup 1.0000x reference)
//
#include <hip/hip_runtime.h>

#define NUM_DENSE 13
#define NUM_SPARSE 26
#define FEAT_NUM 40000
#define FEATURE_LENGTH (NUM_SPARSE * FEAT_NUM + NUM_DENSE)  // 1,040,013
#define KDIM 64
#define BATCH 4096
#define QSIZE 4000          // floats per LDS chunk: 10 chunks per 40000-window
#define NCHUNK 10
#define LDSN (QSIZE + 4)    // 4004 floats = 16,016 B
#define NT 1024
#define NG 8                // j-groups -> 512 blocks = 2 blocks/CU
#define NBUF 4              // 4-deep LDS ring, 2-stage lookahead
#define NPASS 3             // DIAGNOSTIC: 3x V-stream so accum outranks the 160us
                            // harness fills and surfaces in the top-5 counter table.
                            // Passes 1-2 accumulate into dummies folded with an
                            // asm-opaque zero -> bit-identical output, no DCE.

// Kernel 0: transpose sparse indices to [slot][batch] (raw 0..39999 values).
__global__ void transpose_kernel(const int* __restrict__ sp, int* __restrict__ sp_t) {
    int tid = blockIdx.x * blockDim.x + threadIdx.x;  // tid = j*BATCH + b
    int j = tid >> 12;
    int b = tid & 4095;
    sp_t[tid] = sp[b * NUM_SPARSE + j];
}

// async global->LDS, 16B per lane; HW dest = wave-uniform(base) + lane*16.
__device__ __forceinline__ void load_lds16(const float4* g, float* l) {
    __builtin_amdgcn_global_load_lds(
        (const __attribute__((address_space(1))) void*)g,
        (__attribute__((address_space(3))) void*)l, 16, 0, 0);
}

// Kernel 1: 4-buffer ring, counted-vmcnt pipeline (R2-passed structure),
// wrapped in NPASS diagnostic passes.
__global__ __launch_bounds__(NT, 8) void accum_kernel(const float* __restrict__ V,
                                                      const int* __restrict__ sp_t,
                                                      float* __restrict__ PS,
                                                      float* __restrict__ PQ) {
    __shared__ __align__(16) float buf[NBUF][LDSN];   // 4 x 16,016 B = 64 KB

    const int k = blockIdx.x;
    const int g = blockIdx.y;
    const int tid = threadIdx.x;
    const int jstart = (g * NUM_SPARSE) / NG;        // 0,3,6,9,13,16,19,22
    const int jend   = ((g + 1) * NUM_SPARSE) / NG;
    const int nw     = jend - jstart;                // 3 or 4 windows

    const size_t kbase = (size_t)k * FEATURE_LENGTH + NUM_DENSE;
    const int a   = (int)(kbase & 3);        // k=63 -> 0 (exact end, no OOB)
    const int nl4 = (QSIZE + a + 3) >> 2;    // 1000 or 1001 float4 per chunk
    const int nstage = nw * NCHUNK;

    // preload ALL window indices into named registers (no vmem in main loop)
    int s0[4], s1[4], s2[4], s3[4];
#pragma unroll
    for (int r = 0; r < 4; ++r) {
        s0[r] = sp_t[(jstart + 0) * BATCH + tid + NT * r];
        s1[r] = sp_t[(jstart + 1) * BATCH + tid + NT * r];
        s2[r] = sp_t[(jstart + 2) * BATCH + tid + NT * r];
    }
    if (nw == 4) {
#pragma unroll
        for (int r = 0; r < 4; ++r) s3[r] = sp_t[(jstart + 3) * BATCH + tid + NT * r];
    } else {
#pragma unroll
        for (int r = 0; r < 4; ++r) s3[r] = 0;
    }

    float sAcc[4]  = {0.f, 0.f, 0.f, 0.f};
    float qAcc[4]  = {0.f, 0.f, 0.f, 0.f};
    float sAccD[4] = {0.f, 0.f, 0.f, 0.f};   // dummy accumulators (passes 1-2)
    float qAccD[4] = {0.f, 0.f, 0.f, 0.f};

    auto issue = [&](int t) {
        const int w_ = t / NCHUNK;
        const int q_ = t - w_ * NCHUNK;
        const float4* __restrict__ g4 =
            (const float4*)(V + (kbase + (size_t)(jstart + w_) * FEAT_NUM
                                       + (size_t)q_ * QSIZE) - a);
        if (tid < nl4)   // nl4 >= 1000: every wave issues exactly 1 inst
            load_lds16(g4 + tid, &buf[t & 3][4 * tid]);
    };

    for (int pass = 0; pass < NPASS; ++pass) {
        // pass-start barrier: drains vmcnt to 0 (clean pipeline slate) and
        // orders prior-pass gathers before this pass's issue(0/1) buf writes.
        __syncthreads();

        int cs[4];
#pragma unroll
        for (int r = 0; r < 4; ++r) cs[r] = s0[r];

        issue(0);
        issue(1);

        int wg = 0, qg = 0;
        for (int s = 0; s < nstage; ++s) {
            const int t = s + 2;
            if (t < nstage) issue(t);

            const int ahead = nstage - 1 - s;
            if (ahead >= 2)      asm volatile("s_waitcnt vmcnt(2)" ::: "memory");
            else if (ahead == 1) asm volatile("s_waitcnt vmcnt(1)" ::: "memory");
            else                 asm volatile("s_waitcnt vmcnt(0)" ::: "memory");
            __builtin_amdgcn_s_barrier();
            asm volatile("" ::: "memory");

            const int q0 = qg * QSIZE;
            const float* __restrict__ bb = buf[s & 3];
#pragma unroll
            for (int r = 0; r < 4; ++r) {
                int rel = cs[r] - q0;
                bool in = (rel >= 0) && (rel < QSIZE);
                int addr = in ? (rel + a) : 0;
                float v = bb[addr];
                v = in ? v : 0.f;
                if (pass == 0) { sAcc[r]  += v; qAcc[r]  += v * v; }
                else           { sAccD[r] += v; qAccD[r] += v * v; }
            }

            if (++qg == NCHUNK) {
                qg = 0; ++wg;
                if (wg < nw) {
#pragma unroll
                    for (int r = 0; r < 4; ++r)
                        cs[r] = (wg == 1) ? s1[r] : (wg == 2) ? s2[r] : s3[r];
                }
            }
        }
    }

    // opaque zero: compiler cannot fold z*dummy away -> passes 1-2 stay live,
    // yet the stored value is bit-identical to the single-pass result.
    float z;
    asm volatile("v_mov_b32 %0, 0" : "=v"(z));

    const int base = (g * KDIM + k) * BATCH + tid;   // [g][k][b]
#pragma unroll
    for (int r = 0; r < 4; ++r) {
        PS[base + NT * r] = sAcc[r] + z * sAccD[r];
        PQ[base + NT * r] = qAcc[r] + z * qAccD[r];
    }
}

// Kernel 2: 256 blocks x 256 threads (unchanged, R2-proven).
__global__ __launch_bounds__(256) void final_kernel(const float* __restrict__ dense,
                                                    const float* __restrict__ w0,
                                                    const float* __restrict__ w,
                                                    const float* __restrict__ V,
                                                    const int* __restrict__ sp_t,
                                                    const float* __restrict__ PS,
                                                    const float* __restrict__ PQ,
                                                    float* __restrict__ out) {
    __shared__ float red[16][17];
    const int tid = threadIdx.x;
    const int bi  = tid & 15;
    const int ki  = tid >> 4;                 // 0..15
    const int b   = blockIdx.x * 16 + bi;

    float x[NUM_DENSE], x2[NUM_DENSE];
#pragma unroll
    for (int d = 0; d < NUM_DENSE; ++d) {
        x[d]  = dense[b * NUM_DENSE + d];
        x2[d] = x[d] * x[d];
    }

    float t = 0.f;
#pragma unroll
    for (int kk = 0; kk < 4; ++kk) {
        const int k = ki * 4 + kk;
        float sv = 0.f, qv = 0.f;
#pragma unroll
        for (int g = 0; g < NG; ++g) {
            sv += PS[((g << 6) + k) * BATCH + b];
            qv += PQ[((g << 6) + k) * BATCH + b];
        }
        const float* __restrict__ Vk = V + (size_t)k * FEATURE_LENGTH;
#pragma unroll
        for (int d = 0; d < NUM_DENSE; ++d) {
            float vv = Vk[d];
            sv += x[d] * vv;
            qv += x2[d] * vv * vv;
        }
        t += sv * sv - qv;
    }
    red[bi][ki] = 0.5f * t;
    __syncthreads();

    if (tid < 16) {
        const int bb = blockIdx.x * 16 + tid;
        float acc = w0[0];
#pragma unroll
        for (int i = 0; i < 16; ++i) acc += red[tid][i];
#pragma unroll
        for (int j = 0; j < NUM_SPARSE; ++j)
            acc += w[NUM_DENSE + j * FEAT_NUM + sp_t[j * BATCH + bb]];
#pragma unroll
        for (int d = 0; d < NUM_DENSE; ++d) acc += x[d] * w[d];
        out[bb] = acc;
    }
}

extern "C" void kernel_launch(void* const* d_in, const int* in_sizes, int n_in,
                              void* d_out, int out_size, void* d_ws, size_t ws_size,
                              hipStream_t stream) {
    const float* dense  = (const float*)d_in[0];
    const int*   sparse = (const int*)d_in[1];
    const float* w0     = (const float*)d_in[2];
    const float* w      = (const float*)d_in[3];
    const float* V      = (const float*)d_in[4];
    float* out = (float*)d_out;

    char* ws = (char*)d_ws;
    int*   sp_t = (int*)ws;                               // 26*4096*4 = 425,984 B
    float* PS   = (float*)(ws + (1 << 20));               // 8*64*4096*4 = 8.39 MB
    float* PQ   = (float*)(ws + (1 << 20) + NG * KDIM * BATCH * 4);

    transpose_kernel<<<(NUM_SPARSE * BATCH) / 256, 256, 0, stream>>>(sparse, sp_t);
    accum_kernel<<<dim3(KDIM, NG), NT, 0, stream>>>(V, sp_t, PS, PQ);
    final_kernel<<<BATCH / 16, 256, 0, stream>>>(dense, w0, w, V, sp_t, PS, PQ, out);
}

// Round 9
// 389.428 us; speedup vs baseline: 1.2384x; 1.2384x over previous
//
#include <hip/hip_runtime.h>

#define NUM_DENSE 13
#define NUM_SPARSE 26
#define FEAT_NUM 40000
#define FEATURE_LENGTH (NUM_SPARSE * FEAT_NUM + NUM_DENSE)  // 1,040,013
#define KDIM 64
#define BATCH 4096
#define QSIZE 4000          // floats per chunk: 10 chunks per 40000-window
#define NCHUNK 10
#define LDSN (QSIZE + 4)    // 4004 floats = 16,016 B
#define NT 1024
#define NG 8                // 64 k x 8 g = 512 blocks = 2 blocks/CU
#define NBUF 4              // LDS ring
#define LA 4                // register-stage lookahead (stages in flight)

// Kernel 0: transpose sparse indices to [slot][batch].
__global__ void transpose_kernel(const int* __restrict__ sp, int* __restrict__ sp_t) {
    int tid = blockIdx.x * blockDim.x + threadIdx.x;
    int j = tid >> 12;
    int b = tid & 4095;
    sp_t[tid] = sp[b * NUM_SPARSE + j];
}

// Opaque asm global load: the compiler's waitcnt pass cannot see this as a
// vmem op, so it can NEVER insert a vmcnt(0) drain for it at barriers or
// memory-clobbered asm. All vmcnt discipline is manual (ladder below).
// Manual counting stays safe under compiler-added vmem (spills): those are
// NEWER queue entries; our waits target the OLDEST -> only more conservative.
// (float4 as asm OUTPUT works; asm INPUT of 128-bit 'v' does not compile on
// this LLVM -> the LDS write below is a plain store instead.)
__device__ __forceinline__ float4 gload16(const float4* p) {
    float4 r;
    asm volatile("global_load_dwordx4 %0, %1, off"
                 : "=&v"(r)
                 : "v"((const __attribute__((address_space(1))) float4*)p));
    return r;
}

// Plain LDS write (compiler emits ds_write_b128). Being compiler-visible:
//  - it is NOT vmem, so it cannot cause a vmcnt drain;
//  - the waitcnt pass auto-inserts the lgkm wait if a pending ds_write's
//    source reg is about to be overwritten by the next gload16 (hazard that
//    R7 hand-patched);
//  - memory-clobbered asm above (vmcnt ladder) and below (lgkmcnt(0)) pin
//    its position in the pipeline.
__device__ __forceinline__ void swrite16(float* lp, float4 v) {
    *reinterpret_cast<float4*>(lp) = v;
}

// Kernel 1: reg-staged counted-vmcnt pipeline.
// Per stage (one 16KB chunk): 1 asm global_load_dwordx4 per wave (LA=4 ahead),
// vmcnt ladder (steady 3, tail 2/1/0), ds_write_b128 of stage s+1, lgkmcnt(0),
// s_barrier, gather stage s from buf[s&3].
// Race audit:
//  - RAW buf: write(s+1)@iter-s pre-barrier; gather(s+1)@iter-s+1 post-barrier.
//  - WAR buf: gather(s)@iter-s; next write of buf[s&3] is stage s+4 @iter-s+3,
//    separated by barriers at s+1,s+2; gathers drained by iter-s+1's lgkmcnt(0).
//  - NO compiler-tracked vmem inside the loop (indices preloaded to regs), so
//    the compiler cannot emit a vmcnt(0) drain anywhere in the pipeline.
__global__ __launch_bounds__(NT, 8) void accum_kernel(const float* __restrict__ V,
                                                      const int* __restrict__ sp_t,
                                                      float* __restrict__ PS,
                                                      float* __restrict__ PQ) {
    __shared__ __align__(16) float buf[NBUF][LDSN];   // 4 x 16,016 B = 64 KB

    const int k = blockIdx.x;
    const int g = blockIdx.y;
    const int tid = threadIdx.x;
    const int jstart = (g * NUM_SPARSE) / NG;        // 0,3,6,9,13,16,19,22
    const int jend   = ((g + 1) * NUM_SPARSE) / NG;
    const int nw     = jend - jstart;                // 3 or 4 windows

    const size_t kbase = (size_t)k * FEATURE_LENGTH + NUM_DENSE;
    const int a   = (int)(kbase & 3);        // k=63 -> 0 (exact end, no OOB)
    const int nl4 = (QSIZE + a + 3) >> 2;    // 1000 or 1001 float4 per chunk
    const int nstage = nw * NCHUNK;

    // chunk t starts at g4b + t*1000 float4s (40000 = 10*4000, uniform split)
    const float4* g4b = (const float4*)(V + kbase + (size_t)jstart * FEAT_NUM - a) + tid;
    const bool ld = (tid < nl4);   // every wave keeps >=1 active lane (nl4>=1000)

    // preload ALL window indices into named registers (no tracked vmem in loop)
    int s0[4], s1[4], s2[4], s3[4];
#pragma unroll
    for (int r = 0; r < 4; ++r) {
        s0[r] = sp_t[(jstart + 0) * BATCH + tid + NT * r];
        s1[r] = sp_t[(jstart + 1) * BATCH + tid + NT * r];
        s2[r] = sp_t[(jstart + 2) * BATCH + tid + NT * r];
    }
    if (nw == 4) {
#pragma unroll
        for (int r = 0; r < 4; ++r) s3[r] = sp_t[(jstart + 3) * BATCH + tid + NT * r];
    } else {
#pragma unroll
        for (int r = 0; r < 4; ++r) s3[r] = 0;
    }

    float sAcc[4] = {0.f, 0.f, 0.f, 0.f};
    float qAcc[4] = {0.f, 0.f, 0.f, 0.f};
    int cs[4];
#pragma unroll
    for (int r = 0; r < 4; ++r) cs[r] = s0[r];

    __syncthreads();   // drain idx loads: tracked-vmem queue empty entering pipeline

    // prologue: issue stages 0..3, write stage 0 to LDS
    float4 R[4];       // statically indexed after unroll (no scratch)
    if (ld) {
        R[0] = gload16(g4b);
        R[1] = gload16(g4b + 1000);
        R[2] = gload16(g4b + 2000);
        R[3] = gload16(g4b + 3000);
    }
    asm volatile("s_waitcnt vmcnt(3)" ::: "memory");  // stage 0 resident in R[0]
    if (ld) swrite16(&buf[0][4 * tid], R[0]);

    int wg = 0, qg = 0;
    for (int sb = 0; sb < nstage; sb += 4) {
#pragma unroll
        for (int u = 0; u < 4; ++u) {
            const int s = sb + u;
            if (s < nstage) {
                // 1) issue load(s+LA) into the slot stage s vacated
                //    (compiler auto-inserts lgkm wait if R[u]'s ds_write pends)
                if (s + LA < nstage && ld)
                    R[u] = gload16(g4b + (size_t)(s + LA) * 1000);
                // 2) counted wait for stage s+1's load, then stage it to LDS
                if (s + 1 < nstage) {
                    const int pend = (nstage - 2 - s < 3) ? (nstage - 2 - s) : 3;
                    if (pend == 3)      asm volatile("s_waitcnt vmcnt(3)" ::: "memory");
                    else if (pend == 2) asm volatile("s_waitcnt vmcnt(2)" ::: "memory");
                    else if (pend == 1) asm volatile("s_waitcnt vmcnt(1)" ::: "memory");
                    else                asm volatile("s_waitcnt vmcnt(0)" ::: "memory");
                    if (ld) swrite16(&buf[(u + 1) & 3][4 * tid], R[(u + 1) & 3]);
                }
                // 3) writes visible + order gathers (clobbers fence DS ops only;
                //    no tracked vmem exists -> no compiler vmcnt drain possible)
                asm volatile("s_waitcnt lgkmcnt(0)" ::: "memory");
                __builtin_amdgcn_s_barrier();
                asm volatile("" ::: "memory");

                // 4) gather stage s
                const int q0 = qg * QSIZE;
                const float* __restrict__ bb = buf[u];
#pragma unroll
                for (int r = 0; r < 4; ++r) {
                    int rel = cs[r] - q0;
                    bool in = (rel >= 0) && (rel < QSIZE);
                    int addr = in ? (rel + a) : 0;   // masked: broadcast read, free
                    float v = bb[addr];
                    v = in ? v : 0.f;
                    sAcc[r] += v;
                    qAcc[r] += v * v;
                }
                if (++qg == NCHUNK) {
                    qg = 0; ++wg;
                    if (wg < nw) {
#pragma unroll
                        for (int r = 0; r < 4; ++r)
                            cs[r] = (wg == 1) ? s1[r] : (wg == 2) ? s2[r] : s3[r];
                    }
                }
            }
        }
    }

    const int base = (g * KDIM + k) * BATCH + tid;   // [g][k][b]
#pragma unroll
    for (int r = 0; r < 4; ++r) {
        PS[base + NT * r] = sAcc[r];
        PQ[base + NT * r] = qAcc[r];
    }
}

// Kernel 2: 256 blocks x 256 threads (unchanged, proven).
__global__ __launch_bounds__(256) void final_kernel(const float* __restrict__ dense,
                                                    const float* __restrict__ w0,
                                                    const float* __restrict__ w,
                                                    const float* __restrict__ V,
                                                    const int* __restrict__ sp_t,
                                                    const float* __restrict__ PS,
                                                    const float* __restrict__ PQ,
                                                    float* __restrict__ out) {
    __shared__ float red[16][17];
    const int tid = threadIdx.x;
    const int bi  = tid & 15;
    const int ki  = tid >> 4;
    const int b   = blockIdx.x * 16 + bi;

    float x[NUM_DENSE], x2[NUM_DENSE];
#pragma unroll
    for (int d = 0; d < NUM_DENSE; ++d) {
        x[d]  = dense[b * NUM_DENSE + d];
        x2[d] = x[d] * x[d];
    }

    float t = 0.f;
#pragma unroll
    for (int kk = 0; kk < 4; ++kk) {
        const int k = ki * 4 + kk;
        float sv = 0.f, qv = 0.f;
#pragma unroll
        for (int g = 0; g < NG; ++g) {
            sv += PS[((g << 6) + k) * BATCH + b];
            qv += PQ[((g << 6) + k) * BATCH + b];
        }
        const float* __restrict__ Vk = V + (size_t)k * FEATURE_LENGTH;
#pragma unroll
        for (int d = 0; d < NUM_DENSE; ++d) {
            float vv = Vk[d];
            sv += x[d] * vv;
            qv += x2[d] * vv * vv;
        }
        t += sv * sv - qv;
    }
    red[bi][ki] = 0.5f * t;
    __syncthreads();

    if (tid < 16) {
        const int bb = blockIdx.x * 16 + tid;
        float acc = w0[0];
#pragma unroll
        for (int i = 0; i < 16; ++i) acc += red[tid][i];
#pragma unroll
        for (int j = 0; j < NUM_SPARSE; ++j)
            acc += w[NUM_DENSE + j * FEAT_NUM + sp_t[j * BATCH + bb]];
#pragma unroll
        for (int d = 0; d < NUM_DENSE; ++d) acc += x[d] * w[d];
        out[bb] = acc;
    }
}

extern "C" void kernel_launch(void* const* d_in, const int* in_sizes, int n_in,
                              void* d_out, int out_size, void* d_ws, size_t ws_size,
                              hipStream_t stream) {
    const float* dense  = (const float*)d_in[0];
    const int*   sparse = (const int*)d_in[1];
    const float* w0     = (const float*)d_in[2];
    const float* w      = (const float*)d_in[3];
    const float* V      = (const float*)d_in[4];
    float* out = (float*)d_out;

    char* ws = (char*)d_ws;
    int*   sp_t = (int*)ws;                               // 26*4096*4 = 425,984 B
    float* PS   = (float*)(ws + (1 << 20));               // 8*64*4096*4 = 8.39 MB
    float* PQ   = (float*)(ws + (1 << 20) + NG * KDIM * BATCH * 4);

    transpose_kernel<<<(NUM_SPARSE * BATCH) / 256, 256, 0, stream>>>(sparse, sp_t);
    accum_kernel<<<dim3(KDIM, NG), NT, 0, stream>>>(V, sp_t, PS, PQ);
    final_kernel<<<BATCH / 16, 256, 0, stream>>>(dense, w0, w, V, sp_t, PS, PQ, out);
}